// Round 1
// baseline (639.471 us; speedup 1.0000x reference)
//
#include <hip/hip_runtime.h>
#include <math.h>

#define N_NODES 50000
#define N_EDGES 800000
#define IN_DIM_N 128
#define IN_DIM_E 32
#define OUT_DIM 128

// ---------------- init: m = -inf, denom = 0 ----------------
__global__ void init_kernel(float* __restrict__ m, float* __restrict__ denom) {
    int i = blockIdx.x * blockDim.x + threadIdx.x;
    if (i < N_NODES) { m[i] = -INFINITY; denom[i] = 0.0f; }
}

// ---------------- transpose W (128x128) so GEMM stages conflict-free ----------------
__global__ void transpose_w_kernel(const float* __restrict__ W, float* __restrict__ Wt) {
    int i = blockIdx.x * 256 + threadIdx.x;   // 16384 total
    if (i < 128 * 128) {
        int c = i >> 7, k = i & 127;
        Wt[k * 128 + c] = W[i];               // coalesced read, strided write (64KB once)
    }
}

// ---------------- z = A @ W^T, fused s_src = z@a_src, s_dst = z@a_dst ----------------
#define GEMM_ROWS 16
__launch_bounds__(256)
__global__ void gemm_kernel(const float* __restrict__ A, const float* __restrict__ Wt,
                            const float* __restrict__ attn,
                            float* __restrict__ z, float* __restrict__ s_src,
                            float* __restrict__ s_dst) {
    __shared__ float Wl[128 * 132];            // Wt[k][c], row stride 132 (16B-aligned, pad)
    __shared__ float Al[GEMM_ROWS * 128];
    __shared__ float asrc[128], adst[128];
    int tid = threadIdx.x;

    // stage Wt: rows k coalesced -> LDS conflict-free float4 writes
    for (int i = tid; i < 128 * 32; i += 256) {
        int k = i >> 5, q = i & 31;
        float4 v = ((const float4*)Wt)[k * 32 + q];
        *((float4*)&Wl[k * 132 + q * 4]) = v;
    }
    if (tid < 128) { asrc[tid] = attn[tid]; adst[tid] = attn[160 + tid]; }

    int row0 = blockIdx.x * GEMM_ROWS;
    for (int i = tid; i < GEMM_ROWS * 32; i += 256) {
        int r = i >> 5, q = i & 31;
        int gr = row0 + r;
        float4 v = make_float4(0.f, 0.f, 0.f, 0.f);
        if (gr < N_NODES) v = ((const float4*)A)[gr * 32 + q];
        *((float4*)&Al[r * 128 + q * 4]) = v;
    }
    __syncthreads();

    int lane_c = (tid & 31) * 4;   // column base (0..124)
    int r_local = tid >> 5;        // 0..7 ; also handles r_local+8
    const float* A0 = &Al[r_local * 128];
    const float* A1 = &Al[(r_local + 8) * 128];
    float4 acc0 = make_float4(0.f, 0.f, 0.f, 0.f);
    float4 acc1 = make_float4(0.f, 0.f, 0.f, 0.f);

    for (int k = 0; k < 128; ++k) {
        float4 wv = *((const float4*)&Wl[k * 132 + lane_c]);
        float a0 = A0[k], a1 = A1[k];
        acc0.x = fmaf(a0, wv.x, acc0.x); acc0.y = fmaf(a0, wv.y, acc0.y);
        acc0.z = fmaf(a0, wv.z, acc0.z); acc0.w = fmaf(a0, wv.w, acc0.w);
        acc1.x = fmaf(a1, wv.x, acc1.x); acc1.y = fmaf(a1, wv.y, acc1.y);
        acc1.z = fmaf(a1, wv.z, acc1.z); acc1.w = fmaf(a1, wv.w, acc1.w);
    }

    int gr0 = row0 + r_local, gr1 = row0 + r_local + 8;
    if (gr0 < N_NODES) ((float4*)z)[gr0 * 32 + (tid & 31)] = acc0;
    if (gr1 < N_NODES) ((float4*)z)[gr1 * 32 + (tid & 31)] = acc1;

    // fused attention dots
    float4 as = *((float4*)&asrc[lane_c]);
    float4 ad = *((float4*)&adst[lane_c]);
    float ps0 = acc0.x * as.x + acc0.y * as.y + acc0.z * as.z + acc0.w * as.w;
    float pd0 = acc0.x * ad.x + acc0.y * ad.y + acc0.z * ad.z + acc0.w * ad.w;
    float ps1 = acc1.x * as.x + acc1.y * as.y + acc1.z * as.z + acc1.w * as.w;
    float pd1 = acc1.x * ad.x + acc1.y * ad.y + acc1.z * ad.z + acc1.w * ad.w;
    for (int off = 16; off; off >>= 1) {
        ps0 += __shfl_down(ps0, off, 32);
        pd0 += __shfl_down(pd0, off, 32);
        ps1 += __shfl_down(ps1, off, 32);
        pd1 += __shfl_down(pd1, off, 32);
    }
    if ((tid & 31) == 0) {
        if (gr0 < N_NODES) { s_src[gr0] = ps0; s_dst[gr0] = pd0; }
        if (gr1 < N_NODES) { s_src[gr1] = ps1; s_dst[gr1] = pd1; }
    }
}

// ---------------- per-edge score e = lrelu(...), segment-max via atomics ----------------
__global__ void edge_score_kernel(const float* __restrict__ efeats, const float* __restrict__ attn,
                                  const int* __restrict__ src, const int* __restrict__ dst,
                                  const float* __restrict__ s_src, const float* __restrict__ s_dst,
                                  float* __restrict__ e_out, float* __restrict__ m) {
    int i = blockIdx.x * blockDim.x + threadIdx.x;
    if (i >= N_EDGES) return;
    const float4* ef = (const float4*)(efeats + (long)i * IN_DIM_E);
    const float4* ae = (const float4*)(attn + OUT_DIM);
    float se = 0.f;
#pragma unroll
    for (int q = 0; q < IN_DIM_E / 4; ++q) {
        float4 v = ef[q];
        float4 a = ae[q];
        se += v.x * a.x + v.y * a.y + v.z * a.z + v.w * a.w;
    }
    int s = src[i], d = dst[i];
    float x = s_src[s] + se + s_dst[d];
    float ev = (x >= 0.f) ? x : 0.01f * x;
    e_out[i] = ev;
    // float atomic max (handles mixed signs; m initialized to -inf)
    if (ev >= 0.f) atomicMax((int*)&m[d], __float_as_int(ev));
    else           atomicMin((unsigned int*)&m[d], __float_as_uint(ev));
}

// ---------------- w = exp(e - m[dst]); denom += w ----------------
__global__ void edge_weight_kernel(const int* __restrict__ dst, const float* __restrict__ m,
                                   float* __restrict__ ew, float* __restrict__ denom) {
    int i = blockIdx.x * blockDim.x + threadIdx.x;
    if (i >= N_EDGES) return;
    int d = dst[i];
    float w = expf(ew[i] - m[d]);
    ew[i] = w;
    atomicAdd(&denom[d], w);
}

// ---------------- h[dst] += alpha * z[src], 128 threads per edge ----------------
__launch_bounds__(256)
__global__ void aggregate_kernel(const int* __restrict__ src, const int* __restrict__ dst,
                                 const float* __restrict__ w, const float* __restrict__ denom,
                                 const float* __restrict__ z, float* __restrict__ h) {
    int e = blockIdx.x * 2 + (threadIdx.x >> 7);
    if (e >= N_EDGES) return;
    int c = threadIdx.x & 127;
    int s = src[e], d = dst[e];
    float dn = denom[d];
    float alpha = w[e] / (dn > 0.f ? dn : 1.f);
    atomicAdd(&h[(long)d * OUT_DIM + c], alpha * z[(long)s * OUT_DIM + c]);
}

extern "C" void kernel_launch(void* const* d_in, const int* in_sizes, int n_in,
                              void* d_out, int out_size, void* d_ws, size_t ws_size,
                              hipStream_t stream) {
    const float* nfeats = (const float*)d_in[0];
    const float* efeats = (const float*)d_in[1];
    const float* W_fc   = (const float*)d_in[2];
    const float* W_attn = (const float*)d_in[3];
    const int*   src    = (const int*)d_in[4];
    const int*   dst    = (const int*)d_in[5];
    float* h = (float*)d_out;

    float* ws    = (float*)d_ws;
    float* z     = ws;                       // 6,400,000
    float* s_src = z + (size_t)N_NODES * OUT_DIM;
    float* s_dst = s_src + N_NODES;
    float* m     = s_dst + N_NODES;
    float* denom = m + N_NODES;
    float* e_w   = denom + N_NODES;          // N_EDGES (e, then overwritten by w)
    float* Wt    = e_w + N_EDGES;            // 16384

    hipMemsetAsync(d_out, 0, (size_t)out_size * sizeof(float), stream);
    init_kernel<<<(N_NODES + 255) / 256, 256, 0, stream>>>(m, denom);
    transpose_w_kernel<<<64, 256, 0, stream>>>(W_fc, Wt);
    gemm_kernel<<<(N_NODES + GEMM_ROWS - 1) / GEMM_ROWS, 256, 0, stream>>>(
        nfeats, Wt, W_attn, z, s_src, s_dst);
    edge_score_kernel<<<(N_EDGES + 255) / 256, 256, 0, stream>>>(
        efeats, W_attn, src, dst, s_src, s_dst, e_w, m);
    edge_weight_kernel<<<(N_EDGES + 255) / 256, 256, 0, stream>>>(dst, m, e_w, denom);
    aggregate_kernel<<<(N_EDGES + 1) / 2, 256, 0, stream>>>(src, dst, e_w, denom, z, h);
}

// Round 2
// 485.739 us; speedup vs baseline: 1.3165x; 1.3165x over previous
//
#include <hip/hip_runtime.h>
#include <math.h>

#define N_NODES 50000
#define N_EDGES 800000
#define IN_DIM_N 128
#define IN_DIM_E 32
#define OUT_DIM 128

// ---------------- transpose W (128x128) so GEMM stages conflict-free ----------------
__global__ void transpose_w_kernel(const float* __restrict__ W, float* __restrict__ Wt) {
    int i = blockIdx.x * 256 + threadIdx.x;   // 16384 total
    if (i < 128 * 128) {
        int c = i >> 7, k = i & 127;
        Wt[k * 128 + c] = W[i];               // coalesced read, strided write (64KB once)
    }
}

// ---------------- z = A @ W^T, fused s_src = z@a_src, s_dst = z@a_dst ----------------
#define GEMM_ROWS 16
__launch_bounds__(256)
__global__ void gemm_kernel(const float* __restrict__ A, const float* __restrict__ Wt,
                            const float* __restrict__ attn,
                            float* __restrict__ z, float* __restrict__ s_src,
                            float* __restrict__ s_dst) {
    __shared__ float Wl[128 * 132];            // Wt[k][c], row stride 132 (16B-aligned, pad)
    __shared__ float Al[GEMM_ROWS * 128];
    __shared__ float asrc[128], adst[128];
    int tid = threadIdx.x;

    for (int i = tid; i < 128 * 32; i += 256) {
        int k = i >> 5, q = i & 31;
        float4 v = ((const float4*)Wt)[k * 32 + q];
        *((float4*)&Wl[k * 132 + q * 4]) = v;
    }
    if (tid < 128) { asrc[tid] = attn[tid]; adst[tid] = attn[160 + tid]; }

    int row0 = blockIdx.x * GEMM_ROWS;
    for (int i = tid; i < GEMM_ROWS * 32; i += 256) {
        int r = i >> 5, q = i & 31;
        int gr = row0 + r;
        float4 v = make_float4(0.f, 0.f, 0.f, 0.f);
        if (gr < N_NODES) v = ((const float4*)A)[gr * 32 + q];
        *((float4*)&Al[r * 128 + q * 4]) = v;
    }
    __syncthreads();

    int lane_c = (tid & 31) * 4;
    int r_local = tid >> 5;
    const float* A0 = &Al[r_local * 128];
    const float* A1 = &Al[(r_local + 8) * 128];
    float4 acc0 = make_float4(0.f, 0.f, 0.f, 0.f);
    float4 acc1 = make_float4(0.f, 0.f, 0.f, 0.f);

    for (int k = 0; k < 128; ++k) {
        float4 wv = *((const float4*)&Wl[k * 132 + lane_c]);
        float a0 = A0[k], a1 = A1[k];
        acc0.x = fmaf(a0, wv.x, acc0.x); acc0.y = fmaf(a0, wv.y, acc0.y);
        acc0.z = fmaf(a0, wv.z, acc0.z); acc0.w = fmaf(a0, wv.w, acc0.w);
        acc1.x = fmaf(a1, wv.x, acc1.x); acc1.y = fmaf(a1, wv.y, acc1.y);
        acc1.z = fmaf(a1, wv.z, acc1.z); acc1.w = fmaf(a1, wv.w, acc1.w);
    }

    int gr0 = row0 + r_local, gr1 = row0 + r_local + 8;
    if (gr0 < N_NODES) ((float4*)z)[gr0 * 32 + (tid & 31)] = acc0;
    if (gr1 < N_NODES) ((float4*)z)[gr1 * 32 + (tid & 31)] = acc1;

    float4 as = *((float4*)&asrc[lane_c]);
    float4 ad = *((float4*)&adst[lane_c]);
    float ps0 = acc0.x * as.x + acc0.y * as.y + acc0.z * as.z + acc0.w * as.w;
    float pd0 = acc0.x * ad.x + acc0.y * ad.y + acc0.z * ad.z + acc0.w * ad.w;
    float ps1 = acc1.x * as.x + acc1.y * as.y + acc1.z * as.z + acc1.w * as.w;
    float pd1 = acc1.x * ad.x + acc1.y * ad.y + acc1.z * ad.z + acc1.w * ad.w;
    for (int off = 16; off; off >>= 1) {
        ps0 += __shfl_down(ps0, off, 32);
        pd0 += __shfl_down(pd0, off, 32);
        ps1 += __shfl_down(ps1, off, 32);
        pd1 += __shfl_down(pd1, off, 32);
    }
    if ((tid & 31) == 0) {
        if (gr0 < N_NODES) { s_src[gr0] = ps0; s_dst[gr0] = pd0; }
        if (gr1 < N_NODES) { s_src[gr1] = ps1; s_dst[gr1] = pd1; }
    }
}

// ---------------- per-edge score e = lrelu(...), + dst histogram ----------------
__global__ void edge_score_kernel(const float* __restrict__ efeats, const float* __restrict__ attn,
                                  const int* __restrict__ src, const int* __restrict__ dst,
                                  const float* __restrict__ s_src, const float* __restrict__ s_dst,
                                  float* __restrict__ e_out, int* __restrict__ counts) {
    int i = blockIdx.x * blockDim.x + threadIdx.x;
    if (i >= N_EDGES) return;
    const float4* ef = (const float4*)(efeats + (long)i * IN_DIM_E);
    const float4* ae = (const float4*)(attn + OUT_DIM);
    float se = 0.f;
#pragma unroll
    for (int q = 0; q < IN_DIM_E / 4; ++q) {
        float4 v = ef[q];
        float4 a = ae[q];
        se += v.x * a.x + v.y * a.y + v.z * a.z + v.w * a.w;
    }
    int s = src[i], d = dst[i];
    float x = s_src[s] + se + s_dst[d];
    float ev = (x >= 0.f) ? x : 0.01f * x;
    e_out[i] = ev;
    atomicAdd(&counts[d], 1);
}

// ---------------- single-block scan: counts -> exclusive offsets + cursor ----------------
#define SCAN_T 1024
__launch_bounds__(SCAN_T)
__global__ void scan_kernel(const int* __restrict__ counts, int* __restrict__ offsets,
                            int* __restrict__ cursor) {
    __shared__ int part[SCAN_T];
    int t = threadIdx.x;
    const int chunk = (N_NODES + SCAN_T - 1) / SCAN_T;   // 49
    int b = t * chunk;
    int e = min(b + chunk, N_NODES);
    int s = 0;
    for (int i = b; i < e; ++i) s += counts[i];
    part[t] = s;
    __syncthreads();
    for (int off = 1; off < SCAN_T; off <<= 1) {
        int v = (t >= off) ? part[t - off] : 0;
        __syncthreads();
        part[t] += v;
        __syncthreads();
    }
    int run = part[t] - s;   // exclusive base for this thread's chunk
    for (int i = b; i < e; ++i) {
        offsets[i] = run;
        cursor[i]  = run;
        run += counts[i];
    }
    if (t == SCAN_T - 1) offsets[N_NODES] = run;
}

// ---------------- scatter edge ids into CSR order ----------------
__global__ void scatter_kernel(const int* __restrict__ dst, int* __restrict__ cursor,
                               int* __restrict__ eids) {
    int i = blockIdx.x * blockDim.x + threadIdx.x;
    if (i >= N_EDGES) return;
    int pos = atomicAdd(&cursor[dst[i]], 1);
    eids[pos] = i;
}

// ---------------- one wave per node: softmax-weighted gather of z ----------------
__launch_bounds__(256)
__global__ void aggregate_kernel(const int* __restrict__ eids, const int* __restrict__ offsets,
                                 const float* __restrict__ e_out, const int* __restrict__ src,
                                 const float* __restrict__ z, float* __restrict__ h) {
    int node = blockIdx.x * 4 + (threadIdx.x >> 6);
    if (node >= N_NODES) return;
    int lane = threadIdx.x & 63;
    int beg = offsets[node], end = offsets[node + 1];
    float accx = 0.f, accy = 0.f;
    float dsum = 0.f;
    for (int base = beg; base < end; base += 64) {
        int n = min(64, end - base);
        float w = 0.f;
        int s = 0;
        if (lane < n) {
            int eid = eids[base + lane];
            s = src[eid];
            w = expf(e_out[eid]);      // exp(e)/sum(exp(e)) == exp(e-m)/sum(exp(e-m))
            dsum += w;
        }
        for (int j = 0; j < n; ++j) {
            float wj = __shfl(w, j, 64);
            int   sj = __shfl(s, j, 64);
            float2 zv = ((const float2*)z)[(long)sj * 64 + lane];
            accx = fmaf(wj, zv.x, accx);
            accy = fmaf(wj, zv.y, accy);
        }
    }
    for (int off = 32; off; off >>= 1) dsum += __shfl_xor(dsum, off, 64);
    float scale = 1.f / (dsum > 0.f ? dsum : 1.f);
    ((float2*)h)[(long)node * 64 + lane] = make_float2(accx * scale, accy * scale);
}

extern "C" void kernel_launch(void* const* d_in, const int* in_sizes, int n_in,
                              void* d_out, int out_size, void* d_ws, size_t ws_size,
                              hipStream_t stream) {
    const float* nfeats = (const float*)d_in[0];
    const float* efeats = (const float*)d_in[1];
    const float* W_fc   = (const float*)d_in[2];
    const float* W_attn = (const float*)d_in[3];
    const int*   src    = (const int*)d_in[4];
    const int*   dst    = (const int*)d_in[5];
    float* h = (float*)d_out;

    float* ws    = (float*)d_ws;
    float* z     = ws;                                   // 6,400,000 f
    float* s_src = z + (size_t)N_NODES * OUT_DIM;        // 50,000
    float* s_dst = s_src + N_NODES;                      // 50,000
    float* e_out = s_dst + N_NODES;                      // 800,000
    float* Wt    = e_out + N_EDGES;                      // 16,384
    int*   counts  = (int*)(Wt + 128 * 128);             // 50,000
    int*   offsets = counts + N_NODES;                   // 50,001
    int*   cursor  = offsets + N_NODES + 1;              // 50,000
    int*   eids    = cursor + N_NODES;                   // 800,000

    hipMemsetAsync(counts, 0, N_NODES * sizeof(int), stream);
    transpose_w_kernel<<<64, 256, 0, stream>>>(W_fc, Wt);
    gemm_kernel<<<(N_NODES + GEMM_ROWS - 1) / GEMM_ROWS, 256, 0, stream>>>(
        nfeats, Wt, W_attn, z, s_src, s_dst);
    edge_score_kernel<<<(N_EDGES + 255) / 256, 256, 0, stream>>>(
        efeats, W_attn, src, dst, s_src, s_dst, e_out, counts);
    scan_kernel<<<1, SCAN_T, 0, stream>>>(counts, offsets, cursor);
    scatter_kernel<<<(N_EDGES + 255) / 256, 256, 0, stream>>>(dst, cursor, eids);
    aggregate_kernel<<<(N_NODES + 3) / 4, 256, 0, stream>>>(eids, offsets, e_out, src, z, h);
}

// Round 3
// 386.658 us; speedup vs baseline: 1.6538x; 1.2562x over previous
//
#include <hip/hip_runtime.h>
#include <math.h>

#define N_NODES 50000
#define N_EDGES 800000
#define IN_DIM_N 128
#define IN_DIM_E 32
#define OUT_DIM 128
#define SCAN_BLOCKS ((N_NODES + 255) / 256)   // 196

// ---------------- transpose W (128x128) so GEMM stages conflict-free ----------------
__global__ void transpose_w_kernel(const float* __restrict__ W, float* __restrict__ Wt) {
    int i = blockIdx.x * 256 + threadIdx.x;   // 16384 total
    if (i < 128 * 128) {
        int c = i >> 7, k = i & 127;
        Wt[k * 128 + c] = W[i];               // coalesced read, strided write (64KB once)
    }
}

// ---------------- z = A @ W^T, fused s_src = z@a_src, s_dst = z@a_dst ----------------
#define GEMM_ROWS 16
__launch_bounds__(256)
__global__ void gemm_kernel(const float* __restrict__ A, const float* __restrict__ Wt,
                            const float* __restrict__ attn,
                            float* __restrict__ z, float* __restrict__ s_src,
                            float* __restrict__ s_dst) {
    __shared__ float Wl[128 * 132];            // Wt[k][c], row stride 132 (16B-aligned, pad)
    __shared__ float Al[GEMM_ROWS * 128];
    __shared__ float asrc[128], adst[128];
    int tid = threadIdx.x;

    for (int i = tid; i < 128 * 32; i += 256) {
        int k = i >> 5, q = i & 31;
        float4 v = ((const float4*)Wt)[k * 32 + q];
        *((float4*)&Wl[k * 132 + q * 4]) = v;
    }
    if (tid < 128) { asrc[tid] = attn[tid]; adst[tid] = attn[160 + tid]; }

    int row0 = blockIdx.x * GEMM_ROWS;
    for (int i = tid; i < GEMM_ROWS * 32; i += 256) {
        int r = i >> 5, q = i & 31;
        int gr = row0 + r;
        float4 v = make_float4(0.f, 0.f, 0.f, 0.f);
        if (gr < N_NODES) v = ((const float4*)A)[gr * 32 + q];
        *((float4*)&Al[r * 128 + q * 4]) = v;
    }
    __syncthreads();

    int lane_c = (tid & 31) * 4;
    int r_local = tid >> 5;
    const float* A0 = &Al[r_local * 128];
    const float* A1 = &Al[(r_local + 8) * 128];
    float4 acc0 = make_float4(0.f, 0.f, 0.f, 0.f);
    float4 acc1 = make_float4(0.f, 0.f, 0.f, 0.f);

    for (int k = 0; k < 128; ++k) {
        float4 wv = *((const float4*)&Wl[k * 132 + lane_c]);
        float a0 = A0[k], a1 = A1[k];
        acc0.x = fmaf(a0, wv.x, acc0.x); acc0.y = fmaf(a0, wv.y, acc0.y);
        acc0.z = fmaf(a0, wv.z, acc0.z); acc0.w = fmaf(a0, wv.w, acc0.w);
        acc1.x = fmaf(a1, wv.x, acc1.x); acc1.y = fmaf(a1, wv.y, acc1.y);
        acc1.z = fmaf(a1, wv.z, acc1.z); acc1.w = fmaf(a1, wv.w, acc1.w);
    }

    int gr0 = row0 + r_local, gr1 = row0 + r_local + 8;
    if (gr0 < N_NODES) ((float4*)z)[gr0 * 32 + (tid & 31)] = acc0;
    if (gr1 < N_NODES) ((float4*)z)[gr1 * 32 + (tid & 31)] = acc1;

    float4 as = *((float4*)&asrc[lane_c]);
    float4 ad = *((float4*)&adst[lane_c]);
    float ps0 = acc0.x * as.x + acc0.y * as.y + acc0.z * as.z + acc0.w * as.w;
    float pd0 = acc0.x * ad.x + acc0.y * ad.y + acc0.z * ad.z + acc0.w * ad.w;
    float ps1 = acc1.x * as.x + acc1.y * as.y + acc1.z * as.z + acc1.w * as.w;
    float pd1 = acc1.x * ad.x + acc1.y * ad.y + acc1.z * ad.z + acc1.w * ad.w;
    for (int off = 16; off; off >>= 1) {
        ps0 += __shfl_down(ps0, off, 32);
        pd0 += __shfl_down(pd0, off, 32);
        ps1 += __shfl_down(ps1, off, 32);
        pd1 += __shfl_down(pd1, off, 32);
    }
    if ((tid & 31) == 0) {
        if (gr0 < N_NODES) { s_src[gr0] = ps0; s_dst[gr0] = pd0; }
        if (gr1 < N_NODES) { s_src[gr1] = ps1; s_dst[gr1] = pd1; }
    }
}

// ---------------- per-edge score e = lrelu(...), + dst histogram ----------------
__global__ void edge_score_kernel(const float* __restrict__ efeats, const float* __restrict__ attn,
                                  const int* __restrict__ src, const int* __restrict__ dst,
                                  const float* __restrict__ s_src, const float* __restrict__ s_dst,
                                  float* __restrict__ e_out, int* __restrict__ counts) {
    int i = blockIdx.x * blockDim.x + threadIdx.x;
    if (i >= N_EDGES) return;
    const float4* ef = (const float4*)(efeats + (long)i * IN_DIM_E);
    const float4* ae = (const float4*)(attn + OUT_DIM);
    float se = 0.f;
#pragma unroll
    for (int q = 0; q < IN_DIM_E / 4; ++q) {
        float4 v = ef[q];
        float4 a = ae[q];
        se += v.x * a.x + v.y * a.y + v.z * a.z + v.w * a.w;
    }
    int s = src[i], d = dst[i];
    float x = s_src[s] + se + s_dst[d];
    float ev = (x >= 0.f) ? x : 0.01f * x;
    e_out[i] = ev;
    atomicAdd(&counts[d], 1);
}

// ---------------- hierarchical scan, pass 1: per-block exclusive prefix + block sums ----
__launch_bounds__(256)
__global__ void scan1_kernel(const int* __restrict__ counts, int* __restrict__ offsets,
                             int* __restrict__ blocksums) {
    int i = blockIdx.x * 256 + threadIdx.x;
    int v = (i < N_NODES) ? counts[i] : 0;
    int lane = threadIdx.x & 63;
    int wv = threadIdx.x >> 6;
    int x = v;
    for (int off = 1; off < 64; off <<= 1) {
        int y = __shfl_up(x, off, 64);
        if (lane >= off) x += y;
    }
    __shared__ int wsum[4];
    if (lane == 63) wsum[wv] = x;
    __syncthreads();
    int base = 0;
    for (int w = 0; w < wv; ++w) base += wsum[w];
    if (i < N_NODES) offsets[i] = base + x - v;           // block-local exclusive
    if (threadIdx.x == 255) blocksums[blockIdx.x] = base + x;
}

// ---------------- scan pass 2: exclusive scan of 196 block sums (1 block) ----------------
__launch_bounds__(256)
__global__ void scan2_kernel(int* __restrict__ blocksums) {
    int t = threadIdx.x;
    int v = (t < SCAN_BLOCKS) ? blocksums[t] : 0;
    int lane = t & 63;
    int wv = t >> 6;
    int x = v;
    for (int off = 1; off < 64; off <<= 1) {
        int y = __shfl_up(x, off, 64);
        if (lane >= off) x += y;
    }
    __shared__ int wsum[4];
    if (lane == 63) wsum[wv] = x;
    __syncthreads();
    int base = 0;
    for (int w = 0; w < wv; ++w) base += wsum[w];
    if (t < SCAN_BLOCKS) blocksums[t] = base + x - v;     // exclusive
}

// ---------------- scan pass 3: add block bases, mirror to cursor ----------------
__launch_bounds__(256)
__global__ void scan3_kernel(int* __restrict__ offsets, const int* __restrict__ blocksums,
                             int* __restrict__ cursor) {
    int i = blockIdx.x * 256 + threadIdx.x;
    if (i < N_NODES) {
        int o = offsets[i] + blocksums[blockIdx.x];
        offsets[i] = o;
        cursor[i] = o;
    }
    if (i == 0) offsets[N_NODES] = N_EDGES;
}

// ---------------- scatter edge ids into CSR order ----------------
__global__ void scatter_kernel(const int* __restrict__ dst, int* __restrict__ cursor,
                               int* __restrict__ eids) {
    int i = blockIdx.x * blockDim.x + threadIdx.x;
    if (i >= N_EDGES) return;
    int pos = atomicAdd(&cursor[dst[i]], 1);
    eids[pos] = i;
}

// ---------------- one wave per node: softmax-weighted gather of z ----------------
__launch_bounds__(256)
__global__ void aggregate_kernel(const int* __restrict__ eids, const int* __restrict__ offsets,
                                 const float* __restrict__ e_out, const int* __restrict__ src,
                                 const float* __restrict__ z, float* __restrict__ h) {
    int node = blockIdx.x * 4 + (threadIdx.x >> 6);
    if (node >= N_NODES) return;
    int lane = threadIdx.x & 63;
    int beg = offsets[node], end = offsets[node + 1];
    float accx = 0.f, accy = 0.f;
    float dsum = 0.f;
    for (int base = beg; base < end; base += 64) {
        int n = min(64, end - base);
        float w = 0.f;
        int s = 0;
        if (lane < n) {
            int eid = eids[base + lane];
            s = src[eid];
            w = expf(e_out[eid]);      // exp(e)/sum(exp(e)) == exp(e-m)/sum(exp(e-m))
            dsum += w;
        }
        for (int j = 0; j < n; ++j) {
            float wj = __shfl(w, j, 64);
            int   sj = __shfl(s, j, 64);
            float2 zv = ((const float2*)z)[(long)sj * 64 + lane];
            accx = fmaf(wj, zv.x, accx);
            accy = fmaf(wj, zv.y, accy);
        }
    }
    for (int off = 32; off; off >>= 1) dsum += __shfl_xor(dsum, off, 64);
    float scale = 1.f / (dsum > 0.f ? dsum : 1.f);
    ((float2*)h)[(long)node * 64 + lane] = make_float2(accx * scale, accy * scale);
}

extern "C" void kernel_launch(void* const* d_in, const int* in_sizes, int n_in,
                              void* d_out, int out_size, void* d_ws, size_t ws_size,
                              hipStream_t stream) {
    const float* nfeats = (const float*)d_in[0];
    const float* efeats = (const float*)d_in[1];
    const float* W_fc   = (const float*)d_in[2];
    const float* W_attn = (const float*)d_in[3];
    const int*   src    = (const int*)d_in[4];
    const int*   dst    = (const int*)d_in[5];
    float* h = (float*)d_out;

    float* ws    = (float*)d_ws;
    float* z     = ws;                                   // 6,400,000 f
    float* s_src = z + (size_t)N_NODES * OUT_DIM;        // 50,000
    float* s_dst = s_src + N_NODES;                      // 50,000
    float* e_out = s_dst + N_NODES;                      // 800,000
    float* Wt    = e_out + N_EDGES;                      // 16,384
    int*   counts    = (int*)(Wt + 128 * 128);           // 50,000
    int*   offsets   = counts + N_NODES;                 // 50,001
    int*   cursor    = offsets + N_NODES + 1;            // 50,000
    int*   eids      = cursor + N_NODES;                 // 800,000
    int*   blocksums = eids + N_EDGES;                   // SCAN_BLOCKS

    hipMemsetAsync(counts, 0, N_NODES * sizeof(int), stream);
    transpose_w_kernel<<<64, 256, 0, stream>>>(W_fc, Wt);
    gemm_kernel<<<(N_NODES + GEMM_ROWS - 1) / GEMM_ROWS, 256, 0, stream>>>(
        nfeats, Wt, W_attn, z, s_src, s_dst);
    edge_score_kernel<<<(N_EDGES + 255) / 256, 256, 0, stream>>>(
        efeats, W_attn, src, dst, s_src, s_dst, e_out, counts);
    scan1_kernel<<<SCAN_BLOCKS, 256, 0, stream>>>(counts, offsets, blocksums);
    scan2_kernel<<<1, 256, 0, stream>>>(blocksums);
    scan3_kernel<<<SCAN_BLOCKS, 256, 0, stream>>>(offsets, blocksums, cursor);
    scatter_kernel<<<(N_EDGES + 255) / 256, 256, 0, stream>>>(dst, cursor, eids);
    aggregate_kernel<<<(N_NODES + 3) / 4, 256, 0, stream>>>(eids, offsets, e_out, src, z, h);
}

// Round 4
// 357.302 us; speedup vs baseline: 1.7897x; 1.0822x over previous
//
#include <hip/hip_runtime.h>
#include <math.h>

#define N_NODES 50000
#define N_EDGES 800000
#define IN_DIM_N 128
#define IN_DIM_E 32
#define OUT_DIM 128
#define SCAN_BLOCKS ((N_NODES + 255) / 256)   // 196

// bf16 pack helpers (RNE, no NaN handling needed for this data)
__device__ inline unsigned bf16_rne(float x) {
    unsigned u = __float_as_uint(x);
    return (u + 0x7FFFu + ((u >> 16) & 1u)) >> 16;
}
__device__ inline unsigned pack_bf2(float a, float b) {
    return bf16_rne(a) | (bf16_rne(b) << 16);
}

// ---------------- transpose W (128x128) ----------------
__global__ void transpose_w_kernel(const float* __restrict__ W, float* __restrict__ Wt) {
    int i = blockIdx.x * 256 + threadIdx.x;
    if (i < 128 * 128) {
        int c = i >> 7, k = i & 127;
        Wt[k * 128 + c] = W[i];
    }
}

// ---------------- dst histogram ----------------
__global__ void hist_kernel(const int* __restrict__ dst, int* __restrict__ counts) {
    int i = blockIdx.x * blockDim.x + threadIdx.x;
    if (i < N_EDGES) atomicAdd(&counts[dst[i]], 1);
}

// ---------------- z = A @ W^T (bf16 store), fused s_src/s_dst ----------------
#define GEMM_ROWS 16
__launch_bounds__(256)
__global__ void gemm_kernel(const float* __restrict__ A, const float* __restrict__ Wt,
                            const float* __restrict__ attn,
                            unsigned* __restrict__ zb, float* __restrict__ s_src,
                            float* __restrict__ s_dst) {
    __shared__ float Wl[128 * 132];
    __shared__ float Al[GEMM_ROWS * 128];
    __shared__ float asrc[128], adst[128];
    int tid = threadIdx.x;

    for (int i = tid; i < 128 * 32; i += 256) {
        int k = i >> 5, q = i & 31;
        float4 v = ((const float4*)Wt)[k * 32 + q];
        *((float4*)&Wl[k * 132 + q * 4]) = v;
    }
    if (tid < 128) { asrc[tid] = attn[tid]; adst[tid] = attn[160 + tid]; }

    int row0 = blockIdx.x * GEMM_ROWS;
    for (int i = tid; i < GEMM_ROWS * 32; i += 256) {
        int r = i >> 5, q = i & 31;
        int gr = row0 + r;
        float4 v = make_float4(0.f, 0.f, 0.f, 0.f);
        if (gr < N_NODES) v = ((const float4*)A)[gr * 32 + q];
        *((float4*)&Al[r * 128 + q * 4]) = v;
    }
    __syncthreads();

    int lane_c = (tid & 31) * 4;
    int r_local = tid >> 5;
    const float* A0 = &Al[r_local * 128];
    const float* A1 = &Al[(r_local + 8) * 128];
    float4 acc0 = make_float4(0.f, 0.f, 0.f, 0.f);
    float4 acc1 = make_float4(0.f, 0.f, 0.f, 0.f);

    for (int k = 0; k < 128; ++k) {
        float4 wv = *((const float4*)&Wl[k * 132 + lane_c]);
        float a0 = A0[k], a1 = A1[k];
        acc0.x = fmaf(a0, wv.x, acc0.x); acc0.y = fmaf(a0, wv.y, acc0.y);
        acc0.z = fmaf(a0, wv.z, acc0.z); acc0.w = fmaf(a0, wv.w, acc0.w);
        acc1.x = fmaf(a1, wv.x, acc1.x); acc1.y = fmaf(a1, wv.y, acc1.y);
        acc1.z = fmaf(a1, wv.z, acc1.z); acc1.w = fmaf(a1, wv.w, acc1.w);
    }

    int gr0 = row0 + r_local, gr1 = row0 + r_local + 8;
    // pack 4 consecutive cols (lane_c..lane_c+3) into uint2: low halfword = even col
    if (gr0 < N_NODES) {
        uint2 p = make_uint2(pack_bf2(acc0.x, acc0.y), pack_bf2(acc0.z, acc0.w));
        ((uint2*)zb)[(long)gr0 * 32 + (tid & 31)] = p;
    }
    if (gr1 < N_NODES) {
        uint2 p = make_uint2(pack_bf2(acc1.x, acc1.y), pack_bf2(acc1.z, acc1.w));
        ((uint2*)zb)[(long)gr1 * 32 + (tid & 31)] = p;
    }

    float4 as = *((float4*)&asrc[lane_c]);
    float4 ad = *((float4*)&adst[lane_c]);
    float ps0 = acc0.x * as.x + acc0.y * as.y + acc0.z * as.z + acc0.w * as.w;
    float pd0 = acc0.x * ad.x + acc0.y * ad.y + acc0.z * ad.z + acc0.w * ad.w;
    float ps1 = acc1.x * as.x + acc1.y * as.y + acc1.z * as.z + acc1.w * as.w;
    float pd1 = acc1.x * ad.x + acc1.y * ad.y + acc1.z * ad.z + acc1.w * ad.w;
    for (int off = 16; off; off >>= 1) {
        ps0 += __shfl_down(ps0, off, 32);
        pd0 += __shfl_down(pd0, off, 32);
        ps1 += __shfl_down(ps1, off, 32);
        pd1 += __shfl_down(pd1, off, 32);
    }
    if ((tid & 31) == 0) {
        if (gr0 < N_NODES) { s_src[gr0] = ps0; s_dst[gr0] = pd0; }
        if (gr1 < N_NODES) { s_src[gr1] = ps1; s_dst[gr1] = pd1; }
    }
}

// ---------------- hierarchical scan pass 1 ----------------
__launch_bounds__(256)
__global__ void scan1_kernel(const int* __restrict__ counts, int* __restrict__ offsets,
                             int* __restrict__ blocksums) {
    int i = blockIdx.x * 256 + threadIdx.x;
    int v = (i < N_NODES) ? counts[i] : 0;
    int lane = threadIdx.x & 63;
    int wv = threadIdx.x >> 6;
    int x = v;
    for (int off = 1; off < 64; off <<= 1) {
        int y = __shfl_up(x, off, 64);
        if (lane >= off) x += y;
    }
    __shared__ int wsum[4];
    if (lane == 63) wsum[wv] = x;
    __syncthreads();
    int base = 0;
    for (int w = 0; w < wv; ++w) base += wsum[w];
    if (i < N_NODES) offsets[i] = base + x - v;
    if (threadIdx.x == 255) blocksums[blockIdx.x] = base + x;
}

// ---------------- scan pass 2 ----------------
__launch_bounds__(256)
__global__ void scan2_kernel(int* __restrict__ blocksums) {
    int t = threadIdx.x;
    int v = (t < SCAN_BLOCKS) ? blocksums[t] : 0;
    int lane = t & 63;
    int wv = t >> 6;
    int x = v;
    for (int off = 1; off < 64; off <<= 1) {
        int y = __shfl_up(x, off, 64);
        if (lane >= off) x += y;
    }
    __shared__ int wsum[4];
    if (lane == 63) wsum[wv] = x;
    __syncthreads();
    int base = 0;
    for (int w = 0; w < wv; ++w) base += wsum[w];
    if (t < SCAN_BLOCKS) blocksums[t] = base + x - v;
}

// ---------------- scan pass 3 ----------------
__launch_bounds__(256)
__global__ void scan3_kernel(int* __restrict__ offsets, const int* __restrict__ blocksums,
                             int* __restrict__ cursor) {
    int i = blockIdx.x * 256 + threadIdx.x;
    if (i < N_NODES) {
        int o = offsets[i] + blocksums[blockIdx.x];
        offsets[i] = o;
        cursor[i] = o;
    }
    if (i == 0) offsets[N_NODES] = N_EDGES;
}

// ------- fused: edge score + exp + scatter packed (src, w) into CSR slot -------
__global__ void edge_scatter_kernel(const float* __restrict__ efeats, const float* __restrict__ attn,
                                    const int* __restrict__ src, const int* __restrict__ dst,
                                    const float* __restrict__ s_src, const float* __restrict__ s_dst,
                                    int* __restrict__ cursor, float2* __restrict__ pairs) {
    int i = blockIdx.x * blockDim.x + threadIdx.x;
    if (i >= N_EDGES) return;
    const float4* ef = (const float4*)(efeats + (long)i * IN_DIM_E);
    const float4* ae = (const float4*)(attn + OUT_DIM);
    float se = 0.f;
#pragma unroll
    for (int q = 0; q < IN_DIM_E / 4; ++q) {
        float4 v = ef[q];
        float4 a = ae[q];
        se += v.x * a.x + v.y * a.y + v.z * a.z + v.w * a.w;
    }
    int s = src[i], d = dst[i];
    float x = s_src[s] + se + s_dst[d];
    float ev = (x >= 0.f) ? x : 0.01f * x;
    float w = expf(ev);                       // exp(e)/sum == exp(e-m)/sum(exp(e-m))
    int pos = atomicAdd(&cursor[d], 1);
    pairs[pos] = make_float2(__int_as_float(s), w);
}

// ---------------- one wave per node: weighted gather of bf16 z ----------------
__launch_bounds__(256)
__global__ void aggregate_kernel(const float2* __restrict__ pairs, const int* __restrict__ offsets,
                                 const unsigned* __restrict__ zb, float* __restrict__ h) {
    int node = blockIdx.x * 4 + (threadIdx.x >> 6);
    if (node >= N_NODES) return;
    int lane = threadIdx.x & 63;
    int beg = offsets[node], end = offsets[node + 1];
    float accx = 0.f, accy = 0.f;
    float dsum = 0.f;
    for (int base = beg; base < end; base += 64) {
        int n = min(64, end - base);
        float w = 0.f;
        int s = 0;
        if (lane < n) {
            float2 p = pairs[base + lane];
            s = __float_as_int(p.x);
            w = p.y;
            dsum += w;
        }
        for (int j = 0; j < n; ++j) {
            float wj = __shfl(w, j, 64);
            int   sj = __shfl(s, j, 64);
            unsigned u = zb[(long)sj * 64 + lane];
            float zx = __uint_as_float(u << 16);
            float zy = __uint_as_float(u & 0xFFFF0000u);
            accx = fmaf(wj, zx, accx);
            accy = fmaf(wj, zy, accy);
        }
    }
    for (int off = 32; off; off >>= 1) dsum += __shfl_xor(dsum, off, 64);
    float scale = 1.f / (dsum > 0.f ? dsum : 1.f);
    ((float2*)h)[(long)node * 64 + lane] = make_float2(accx * scale, accy * scale);
}

extern "C" void kernel_launch(void* const* d_in, const int* in_sizes, int n_in,
                              void* d_out, int out_size, void* d_ws, size_t ws_size,
                              hipStream_t stream) {
    const float* nfeats = (const float*)d_in[0];
    const float* efeats = (const float*)d_in[1];
    const float* W_fc   = (const float*)d_in[2];
    const float* W_attn = (const float*)d_in[3];
    const int*   src    = (const int*)d_in[4];
    const int*   dst    = (const int*)d_in[5];
    float* h = (float*)d_out;

    char* ws = (char*)d_ws;
    unsigned* zb     = (unsigned*)ws;                              // 50000*64 uints = 12.8 MB
    float* s_src     = (float*)(ws + (size_t)N_NODES * 64 * 4);    // 50,000 f
    float* s_dst     = s_src + N_NODES;                            // 50,000 f
    float* Wt        = s_dst + N_NODES;                            // 16,384 f
    int*   counts    = (int*)(Wt + 128 * 128);                     // 50,000
    int*   offsets   = counts + N_NODES;                           // 50,001
    int*   cursor    = offsets + N_NODES + 1;                      // 50,000
    int*   blocksums = cursor + N_NODES;                           // 196
    float2* pairs    = (float2*)(blocksums + SCAN_BLOCKS + 4);     // 800,000 * 8B

    hipMemsetAsync(counts, 0, N_NODES * sizeof(int), stream);
    transpose_w_kernel<<<64, 256, 0, stream>>>(W_fc, Wt);
    hist_kernel<<<(N_EDGES + 255) / 256, 256, 0, stream>>>(dst, counts);
    scan1_kernel<<<SCAN_BLOCKS, 256, 0, stream>>>(counts, offsets, blocksums);
    scan2_kernel<<<1, 256, 0, stream>>>(blocksums);
    scan3_kernel<<<SCAN_BLOCKS, 256, 0, stream>>>(offsets, blocksums, cursor);
    gemm_kernel<<<(N_NODES + GEMM_ROWS - 1) / GEMM_ROWS, 256, 0, stream>>>(
        nfeats, Wt, W_attn, zb, s_src, s_dst);
    edge_scatter_kernel<<<(N_EDGES + 255) / 256, 256, 0, stream>>>(
        efeats, W_attn, src, dst, s_src, s_dst, cursor, pairs);
    aggregate_kernel<<<(N_NODES + 3) / 4, 256, 0, stream>>>(pairs, offsets, zb, h);
}

// Round 5
// 305.395 us; speedup vs baseline: 2.0939x; 1.1700x over previous
//
#include <hip/hip_runtime.h>
#include <math.h>

#define N_NODES 50000
#define N_EDGES 800000
#define IN_DIM_N 128
#define IN_DIM_E 32
#define OUT_DIM 128
#define SCAN_BLOCKS ((N_NODES + 255) / 256)   // 196

// bf16 pack helpers (RNE; data has no NaN/inf)
__device__ inline unsigned bf16_rne(float x) {
    unsigned u = __float_as_uint(x);
    return (u + 0x7FFFu + ((u >> 16) & 1u)) >> 16;
}
__device__ inline unsigned pack_bf2(float a, float b) {
    return bf16_rne(a) | (bf16_rne(b) << 16);
}

// ---------------- transpose W (128x128) ----------------
__global__ void transpose_w_kernel(const float* __restrict__ W, float* __restrict__ Wt) {
    int i = blockIdx.x * 256 + threadIdx.x;
    if (i < 128 * 128) {
        int c = i >> 7, k = i & 127;
        Wt[k * 128 + c] = W[i];
    }
}

// ---------------- z = A @ W^T (bf16 store), fused s_src/s_dst ----------------
#define GEMM_ROWS 16
__launch_bounds__(256)
__global__ void gemm_kernel(const float* __restrict__ A, const float* __restrict__ Wt,
                            const float* __restrict__ attn,
                            unsigned* __restrict__ zb, float* __restrict__ s_src,
                            float* __restrict__ s_dst) {
    __shared__ float Wl[128 * 132];
    __shared__ float Al[GEMM_ROWS * 128];
    __shared__ float asrc[128], adst[128];
    int tid = threadIdx.x;

    for (int i = tid; i < 128 * 32; i += 256) {
        int k = i >> 5, q = i & 31;
        float4 v = ((const float4*)Wt)[k * 32 + q];
        *((float4*)&Wl[k * 132 + q * 4]) = v;
    }
    if (tid < 128) { asrc[tid] = attn[tid]; adst[tid] = attn[160 + tid]; }

    int row0 = blockIdx.x * GEMM_ROWS;
    for (int i = tid; i < GEMM_ROWS * 32; i += 256) {
        int r = i >> 5, q = i & 31;
        int gr = row0 + r;
        float4 v = make_float4(0.f, 0.f, 0.f, 0.f);
        if (gr < N_NODES) v = ((const float4*)A)[gr * 32 + q];
        *((float4*)&Al[r * 128 + q * 4]) = v;
    }
    __syncthreads();

    int lane_c = (tid & 31) * 4;
    int r_local = tid >> 5;
    const float* A0 = &Al[r_local * 128];
    const float* A1 = &Al[(r_local + 8) * 128];
    float4 acc0 = make_float4(0.f, 0.f, 0.f, 0.f);
    float4 acc1 = make_float4(0.f, 0.f, 0.f, 0.f);

    for (int k = 0; k < 128; ++k) {
        float4 wv = *((const float4*)&Wl[k * 132 + lane_c]);
        float a0 = A0[k], a1 = A1[k];
        acc0.x = fmaf(a0, wv.x, acc0.x); acc0.y = fmaf(a0, wv.y, acc0.y);
        acc0.z = fmaf(a0, wv.z, acc0.z); acc0.w = fmaf(a0, wv.w, acc0.w);
        acc1.x = fmaf(a1, wv.x, acc1.x); acc1.y = fmaf(a1, wv.y, acc1.y);
        acc1.z = fmaf(a1, wv.z, acc1.z); acc1.w = fmaf(a1, wv.w, acc1.w);
    }

    int gr0 = row0 + r_local, gr1 = row0 + r_local + 8;
    if (gr0 < N_NODES) {
        uint2 p = make_uint2(pack_bf2(acc0.x, acc0.y), pack_bf2(acc0.z, acc0.w));
        ((uint2*)zb)[(long)gr0 * 32 + (tid & 31)] = p;
    }
    if (gr1 < N_NODES) {
        uint2 p = make_uint2(pack_bf2(acc1.x, acc1.y), pack_bf2(acc1.z, acc1.w));
        ((uint2*)zb)[(long)gr1 * 32 + (tid & 31)] = p;
    }

    float4 as = *((float4*)&asrc[lane_c]);
    float4 ad = *((float4*)&adst[lane_c]);
    float ps0 = acc0.x * as.x + acc0.y * as.y + acc0.z * as.z + acc0.w * as.w;
    float pd0 = acc0.x * ad.x + acc0.y * ad.y + acc0.z * ad.z + acc0.w * ad.w;
    float ps1 = acc1.x * as.x + acc1.y * as.y + acc1.z * as.z + acc1.w * as.w;
    float pd1 = acc1.x * ad.x + acc1.y * ad.y + acc1.z * ad.z + acc1.w * ad.w;
    for (int off = 16; off; off >>= 1) {
        ps0 += __shfl_down(ps0, off, 32);
        pd0 += __shfl_down(pd0, off, 32);
        ps1 += __shfl_down(ps1, off, 32);
        pd1 += __shfl_down(pd1, off, 32);
    }
    if ((tid & 31) == 0) {
        if (gr0 < N_NODES) { s_src[gr0] = ps0; s_dst[gr0] = pd0; }
        if (gr1 < N_NODES) { s_src[gr1] = ps1; s_dst[gr1] = pd1; }
    }
}

// ---- pass 1 over edges: score + exp + histogram-with-rank, all coalesced writes ----
__global__ void edge_score_hist_kernel(const float* __restrict__ efeats, const float* __restrict__ attn,
                                       const int* __restrict__ src, const int* __restrict__ dst,
                                       const float* __restrict__ s_src, const float* __restrict__ s_dst,
                                       int* __restrict__ counts, unsigned short* __restrict__ ranks,
                                       unsigned short* __restrict__ wq) {
    int i = blockIdx.x * blockDim.x + threadIdx.x;
    if (i >= N_EDGES) return;
    const float4* ef = (const float4*)(efeats + (long)i * IN_DIM_E);
    const float4* ae = (const float4*)(attn + OUT_DIM);
    float se = 0.f;
#pragma unroll
    for (int q = 0; q < IN_DIM_E / 4; ++q) {
        float4 v = ef[q];
        float4 a = ae[q];
        se += v.x * a.x + v.y * a.y + v.z * a.z + v.w * a.w;
    }
    int s = src[i], d = dst[i];
    float x = s_src[s] + se + s_dst[d];
    float ev = (x >= 0.f) ? x : 0.01f * x;
    float w = expf(ev);                   // exp(e)/sum == exp(e-m)/sum(exp(e-m))
    wq[i] = (unsigned short)bf16_rne(w);
    ranks[i] = (unsigned short)atomicAdd(&counts[d], 1);   // stable rank within dst
}

// ---------------- hierarchical scan pass 1 ----------------
__launch_bounds__(256)
__global__ void scan1_kernel(const int* __restrict__ counts, int* __restrict__ offsets,
                             int* __restrict__ blocksums) {
    int i = blockIdx.x * 256 + threadIdx.x;
    int v = (i < N_NODES) ? counts[i] : 0;
    int lane = threadIdx.x & 63;
    int wv = threadIdx.x >> 6;
    int x = v;
    for (int off = 1; off < 64; off <<= 1) {
        int y = __shfl_up(x, off, 64);
        if (lane >= off) x += y;
    }
    __shared__ int wsum[4];
    if (lane == 63) wsum[wv] = x;
    __syncthreads();
    int base = 0;
    for (int w = 0; w < wv; ++w) base += wsum[w];
    if (i < N_NODES) offsets[i] = base + x - v;
    if (threadIdx.x == 255) blocksums[blockIdx.x] = base + x;
}

// ---------------- scan pass 2 ----------------
__launch_bounds__(256)
__global__ void scan2_kernel(int* __restrict__ blocksums) {
    int t = threadIdx.x;
    int v = (t < SCAN_BLOCKS) ? blocksums[t] : 0;
    int lane = t & 63;
    int wv = t >> 6;
    int x = v;
    for (int off = 1; off < 64; off <<= 1) {
        int y = __shfl_up(x, off, 64);
        if (lane >= off) x += y;
    }
    __shared__ int wsum[4];
    if (lane == 63) wsum[wv] = x;
    __syncthreads();
    int base = 0;
    for (int w = 0; w < wv; ++w) base += wsum[w];
    if (t < SCAN_BLOCKS) blocksums[t] = base + x - v;
}

// ---------------- scan pass 3 ----------------
__launch_bounds__(256)
__global__ void scan3_kernel(int* __restrict__ offsets, const int* __restrict__ blocksums) {
    int i = blockIdx.x * 256 + threadIdx.x;
    if (i < N_NODES) offsets[i] += blocksums[blockIdx.x];
    if (i == 0) offsets[N_NODES] = N_EDGES;
}

// ---- pass 2 over edges: place packed (src:16 | bf16 w:16) at offsets[d]+rank, no atomics ----
__global__ void scatter_kernel(const int* __restrict__ src, const int* __restrict__ dst,
                               const unsigned short* __restrict__ ranks,
                               const unsigned short* __restrict__ wq,
                               const int* __restrict__ offsets, unsigned* __restrict__ pairs4) {
    int i = blockIdx.x * blockDim.x + threadIdx.x;
    if (i >= N_EDGES) return;
    int d = dst[i];
    int pos = offsets[d] + (int)ranks[i];
    pairs4[pos] = (unsigned)src[i] | ((unsigned)wq[i] << 16);
}

// ---------------- one wave per node: weighted gather of bf16 z ----------------
__launch_bounds__(256)
__global__ void aggregate_kernel(const unsigned* __restrict__ pairs4, const int* __restrict__ offsets,
                                 const unsigned* __restrict__ zb, float* __restrict__ h) {
    int node = blockIdx.x * 4 + (threadIdx.x >> 6);
    if (node >= N_NODES) return;
    int lane = threadIdx.x & 63;
    int beg = offsets[node], end = offsets[node + 1];
    float accx0 = 0.f, accy0 = 0.f, accx1 = 0.f, accy1 = 0.f;
    float dsum = 0.f;
    for (int base = beg; base < end; base += 64) {
        int n = min(64, end - base);
        unsigned u = 0;
        if (lane < n) {
            u = pairs4[base + lane];
            dsum += __uint_as_float(u & 0xFFFF0000u);
        }
        int j = 0;
        for (; j + 1 < n; j += 2) {
            unsigned u0 = (unsigned)__shfl((int)u, j, 64);
            unsigned u1 = (unsigned)__shfl((int)u, j + 1, 64);
            unsigned z0 = zb[(long)(u0 & 0xFFFFu) * 64 + lane];
            unsigned z1 = zb[(long)(u1 & 0xFFFFu) * 64 + lane];
            float w0 = __uint_as_float(u0 & 0xFFFF0000u);
            float w1 = __uint_as_float(u1 & 0xFFFF0000u);
            accx0 = fmaf(w0, __uint_as_float(z0 << 16), accx0);
            accy0 = fmaf(w0, __uint_as_float(z0 & 0xFFFF0000u), accy0);
            accx1 = fmaf(w1, __uint_as_float(z1 << 16), accx1);
            accy1 = fmaf(w1, __uint_as_float(z1 & 0xFFFF0000u), accy1);
        }
        if (j < n) {
            unsigned u0 = (unsigned)__shfl((int)u, j, 64);
            unsigned z0 = zb[(long)(u0 & 0xFFFFu) * 64 + lane];
            float w0 = __uint_as_float(u0 & 0xFFFF0000u);
            accx0 = fmaf(w0, __uint_as_float(z0 << 16), accx0);
            accy0 = fmaf(w0, __uint_as_float(z0 & 0xFFFF0000u), accy0);
        }
    }
    float accx = accx0 + accx1, accy = accy0 + accy1;
    for (int off = 32; off; off >>= 1) dsum += __shfl_xor(dsum, off, 64);
    float scale = 1.f / (dsum > 0.f ? dsum : 1.f);
    ((float2*)h)[(long)node * 64 + lane] = make_float2(accx * scale, accy * scale);
}

extern "C" void kernel_launch(void* const* d_in, const int* in_sizes, int n_in,
                              void* d_out, int out_size, void* d_ws, size_t ws_size,
                              hipStream_t stream) {
    const float* nfeats = (const float*)d_in[0];
    const float* efeats = (const float*)d_in[1];
    const float* W_fc   = (const float*)d_in[2];
    const float* W_attn = (const float*)d_in[3];
    const int*   src    = (const int*)d_in[4];
    const int*   dst    = (const int*)d_in[5];
    float* h = (float*)d_out;

    char* ws = (char*)d_ws;
    unsigned* zb     = (unsigned*)ws;                              // 12.8 MB
    float* s_src     = (float*)(ws + (size_t)N_NODES * 64 * 4);
    float* s_dst     = s_src + N_NODES;
    float* Wt        = s_dst + N_NODES;
    int*   counts    = (int*)(Wt + 128 * 128);
    int*   offsets   = counts + N_NODES;                           // N_NODES+1
    int*   blocksums = offsets + N_NODES + 1;                      // 196
    unsigned short* ranks = (unsigned short*)(blocksums + SCAN_BLOCKS + 4);  // 800k u16
    unsigned short* wq    = ranks + N_EDGES;                       // 800k u16
    unsigned* pairs4      = (unsigned*)(wq + N_EDGES);             // 800k u32

    hipMemsetAsync(counts, 0, N_NODES * sizeof(int), stream);
    transpose_w_kernel<<<64, 256, 0, stream>>>(W_fc, Wt);
    gemm_kernel<<<(N_NODES + GEMM_ROWS - 1) / GEMM_ROWS, 256, 0, stream>>>(
        nfeats, Wt, W_attn, zb, s_src, s_dst);
    edge_score_hist_kernel<<<(N_EDGES + 255) / 256, 256, 0, stream>>>(
        efeats, W_attn, src, dst, s_src, s_dst, counts, ranks, wq);
    scan1_kernel<<<SCAN_BLOCKS, 256, 0, stream>>>(counts, offsets, blocksums);
    scan2_kernel<<<1, 256, 0, stream>>>(blocksums);
    scan3_kernel<<<SCAN_BLOCKS, 256, 0, stream>>>(offsets, blocksums);
    scatter_kernel<<<(N_EDGES + 255) / 256, 256, 0, stream>>>(
        src, dst, ranks, wq, offsets, pairs4);
    aggregate_kernel<<<(N_NODES + 3) / 4, 256, 0, stream>>>(pairs4, offsets, zb, h);
}

// Round 6
// 273.276 us; speedup vs baseline: 2.3400x; 1.1175x over previous
//
#include <hip/hip_runtime.h>
#include <math.h>

#define N_NODES 50000
#define N_EDGES 800000
#define IN_DIM_N 128
#define IN_DIM_E 32
#define OUT_DIM 128
#define SCAN_BLOCKS ((N_NODES + 255) / 256)   // 196

typedef __bf16 bf16x8 __attribute__((ext_vector_type(8)));
typedef float  f32x4  __attribute__((ext_vector_type(4)));

// bf16 pack helpers (RNE; data has no NaN/inf)
__device__ inline unsigned bf16_rne(float x) {
    unsigned u = __float_as_uint(x);
    return (u + 0x7FFFu + ((u >> 16) & 1u)) >> 16;
}
__device__ inline unsigned pack_bf2(float a, float b) {
    return bf16_rne(a) | (bf16_rne(b) << 16);
}

// ---- one-off: W_fc (128x128 fp32, W[c][k]) -> bf16 B-fragment layout ----
// B[k][n] = W[n][k]; frag element (ks, tile, lane, j): k=ks*32+(lane>>4)*8+j,
// n=tile*16+(lane&15). Buffer index ((ks*8+tile)*64+lane)*8+j (bf16), as u32 pairs.
__global__ void wfrag_kernel(const float* __restrict__ W, unsigned* __restrict__ Wfrag) {
    int t = blockIdx.x * 256 + threadIdx.x;   // 0..2047
    if (t >= 2048) return;
    int lane = t & 63;
    int tile = (t >> 6) & 7;
    int ks   = t >> 9;
    int n  = tile * 16 + (lane & 15);
    int kb = ks * 32 + (lane >> 4) * 8;
    const float* srcp = W + n * 128 + kb;     // 8 consecutive k
    unsigned o[4];
#pragma unroll
    for (int j = 0; j < 4; ++j) o[j] = pack_bf2(srcp[2 * j], srcp[2 * j + 1]);
    ((uint4*)Wfrag)[t] = *(uint4*)o;
}

// ---------- MFMA GEMM: 64 rows/block, z bf16 store, fused s_src/s_dst ----------
__launch_bounds__(256)
__global__ void gemm_mfma_kernel(const float* __restrict__ A, const unsigned* __restrict__ Wfrag,
                                 const float* __restrict__ attn, unsigned* __restrict__ zb,
                                 float* __restrict__ s_src, float* __restrict__ s_dst) {
    __shared__ unsigned Au[64 * 68];    // A bf16, row stride 136 bf16 = 68 u32 (pad kills conflicts)
    __shared__ unsigned Bu[8192];       // 32 KB W fragments
    __shared__ float asrc[128], adst[128];
    int tid = threadIdx.x;
    int row0 = blockIdx.x * 64;

    {   // stage W frags (coalesced 16B)
        const uint4* g = (const uint4*)Wfrag;
        uint4* l = (uint4*)Bu;
        for (int i = tid; i < 2048; i += 256) l[i] = g[i];
    }
    if (tid < 128) { asrc[tid] = attn[tid]; adst[tid] = attn[160 + tid]; }

    // stage A: 64 rows x 128 k, fp32 -> bf16
    for (int i = tid; i < 64 * 32; i += 256) {
        int r = i >> 5, q = i & 31;
        int gr = row0 + r;
        float4 v = make_float4(0.f, 0.f, 0.f, 0.f);
        if (gr < N_NODES) v = ((const float4*)A)[(long)gr * 32 + q];
        uint2 p = make_uint2(pack_bf2(v.x, v.y), pack_bf2(v.z, v.w));
        *((uint2*)&Au[r * 68 + q * 2]) = p;
    }
    __syncthreads();

    int lane = tid & 63;
    int wave = tid >> 6;
    int m = lane & 15, quad = lane >> 4;

    f32x4 acc[8];
#pragma unroll
    for (int t = 0; t < 8; ++t) acc[t] = (f32x4){0.f, 0.f, 0.f, 0.f};

#pragma unroll
    for (int ks = 0; ks < 4; ++ks) {
        uint4 au = *((const uint4*)&Au[(wave * 16 + m) * 68 + ks * 16 + quad * 4]);
        bf16x8 af = *(bf16x8*)&au;
#pragma unroll
        for (int t = 0; t < 8; ++t) {
            uint4 bu = *((const uint4*)&Bu[((ks * 8 + t) * 64 + lane) * 4]);
            bf16x8 bf = *(bf16x8*)&bu;
            acc[t] = __builtin_amdgcn_mfma_f32_16x16x32_bf16(af, bf, acc[t], 0, 0, 0);
        }
    }

    // epilogue: C/D layout col=lane&15 (+tile*16), row=quad*4+reg
    float ps[4] = {0.f, 0.f, 0.f, 0.f}, pd[4] = {0.f, 0.f, 0.f, 0.f};
#pragma unroll
    for (int t = 0; t < 8; ++t) {
        float as_ = asrc[t * 16 + m], ad_ = adst[t * 16 + m];
#pragma unroll
        for (int r = 0; r < 4; ++r) {
            float v = acc[t][r];
            ps[r] = fmaf(v, as_, ps[r]);
            pd[r] = fmaf(v, ad_, pd[r]);
            float vn = __shfl_xor(v, 1, 64);      // neighbor col
            if (!(m & 1)) {
                int grow = row0 + wave * 16 + quad * 4 + r;
                if (grow < N_NODES)
                    zb[(long)grow * 64 + t * 8 + (m >> 1)] = pack_bf2(v, vn);
            }
        }
    }
#pragma unroll
    for (int r = 0; r < 4; ++r) {
        for (int off = 1; off < 16; off <<= 1) {
            ps[r] += __shfl_xor(ps[r], off, 64);
            pd[r] += __shfl_xor(pd[r], off, 64);
        }
    }
    if (m == 0) {
#pragma unroll
        for (int r = 0; r < 4; ++r) {
            int grow = row0 + wave * 16 + quad * 4 + r;
            if (grow < N_NODES) { s_src[grow] = ps[r]; s_dst[grow] = pd[r]; }
        }
    }
}

// ---- pass 1 over edges: score + exp + histogram-with-rank, coalesced writes ----
__global__ void edge_score_hist_kernel(const float* __restrict__ efeats, const float* __restrict__ attn,
                                       const int* __restrict__ src, const int* __restrict__ dst,
                                       const float* __restrict__ s_src, const float* __restrict__ s_dst,
                                       int* __restrict__ counts, unsigned short* __restrict__ ranks,
                                       unsigned short* __restrict__ wq) {
    int i = blockIdx.x * blockDim.x + threadIdx.x;
    if (i >= N_EDGES) return;
    const float4* ef = (const float4*)(efeats + (long)i * IN_DIM_E);
    const float4* ae = (const float4*)(attn + OUT_DIM);
    float se = 0.f;
#pragma unroll
    for (int q = 0; q < IN_DIM_E / 4; ++q) {
        float4 v = ef[q];
        float4 a = ae[q];
        se += v.x * a.x + v.y * a.y + v.z * a.z + v.w * a.w;
    }
    int s = src[i], d = dst[i];
    float x = s_src[s] + se + s_dst[d];
    float ev = (x >= 0.f) ? x : 0.01f * x;
    float w = expf(ev);                   // exp(e)/sum == exp(e-m)/sum(exp(e-m))
    wq[i] = (unsigned short)bf16_rne(w);
    ranks[i] = (unsigned short)atomicAdd(&counts[d], 1);   // stable rank within dst
}

// ---------------- hierarchical scan pass 1 ----------------
__launch_bounds__(256)
__global__ void scan1_kernel(const int* __restrict__ counts, int* __restrict__ offsets,
                             int* __restrict__ blocksums) {
    int i = blockIdx.x * 256 + threadIdx.x;
    int v = (i < N_NODES) ? counts[i] : 0;
    int lane = threadIdx.x & 63;
    int wv = threadIdx.x >> 6;
    int x = v;
    for (int off = 1; off < 64; off <<= 1) {
        int y = __shfl_up(x, off, 64);
        if (lane >= off) x += y;
    }
    __shared__ int wsum[4];
    if (lane == 63) wsum[wv] = x;
    __syncthreads();
    int base = 0;
    for (int w = 0; w < wv; ++w) base += wsum[w];
    if (i < N_NODES) offsets[i] = base + x - v;
    if (threadIdx.x == 255) blocksums[blockIdx.x] = base + x;
}

// ---------------- scan pass 2 ----------------
__launch_bounds__(256)
__global__ void scan2_kernel(int* __restrict__ blocksums) {
    int t = threadIdx.x;
    int v = (t < SCAN_BLOCKS) ? blocksums[t] : 0;
    int lane = t & 63;
    int wv = t >> 6;
    int x = v;
    for (int off = 1; off < 64; off <<= 1) {
        int y = __shfl_up(x, off, 64);
        if (lane >= off) x += y;
    }
    __shared__ int wsum[4];
    if (lane == 63) wsum[wv] = x;
    __syncthreads();
    int base = 0;
    for (int w = 0; w < wv; ++w) base += wsum[w];
    if (t < SCAN_BLOCKS) blocksums[t] = base + x - v;
}

// ---------------- scan pass 3 ----------------
__launch_bounds__(256)
__global__ void scan3_kernel(int* __restrict__ offsets, const int* __restrict__ blocksums) {
    int i = blockIdx.x * 256 + threadIdx.x;
    if (i < N_NODES) offsets[i] += blocksums[blockIdx.x];
    if (i == 0) offsets[N_NODES] = N_EDGES;
}

// ---- pass 2 over edges: place packed (src:16 | bf16 w:16) at offsets[d]+rank ----
__global__ void scatter_kernel(const int* __restrict__ src, const int* __restrict__ dst,
                               const unsigned short* __restrict__ ranks,
                               const unsigned short* __restrict__ wq,
                               const int* __restrict__ offsets, unsigned* __restrict__ pairs4) {
    int i = blockIdx.x * blockDim.x + threadIdx.x;
    if (i >= N_EDGES) return;
    int d = dst[i];
    int pos = offsets[d] + (int)ranks[i];
    pairs4[pos] = (unsigned)src[i] | ((unsigned)wq[i] << 16);
}

// ---------------- one wave per node: weighted gather of bf16 z ----------------
__launch_bounds__(256)
__global__ void aggregate_kernel(const unsigned* __restrict__ pairs4, const int* __restrict__ offsets,
                                 const unsigned* __restrict__ zb, float* __restrict__ h) {
    int node = blockIdx.x * 4 + (threadIdx.x >> 6);
    if (node >= N_NODES) return;
    int lane = threadIdx.x & 63;
    int beg = offsets[node], end = offsets[node + 1];
    float accx0 = 0.f, accy0 = 0.f, accx1 = 0.f, accy1 = 0.f;
    float dsum = 0.f;
    for (int base = beg; base < end; base += 64) {
        int n = min(64, end - base);
        unsigned u = 0;
        if (lane < n) {
            u = pairs4[base + lane];
            dsum += __uint_as_float(u & 0xFFFF0000u);
        }
        int j = 0;
        for (; j + 1 < n; j += 2) {
            unsigned u0 = (unsigned)__shfl((int)u, j, 64);
            unsigned u1 = (unsigned)__shfl((int)u, j + 1, 64);
            unsigned z0 = zb[(long)(u0 & 0xFFFFu) * 64 + lane];
            unsigned z1 = zb[(long)(u1 & 0xFFFFu) * 64 + lane];
            float w0 = __uint_as_float(u0 & 0xFFFF0000u);
            float w1 = __uint_as_float(u1 & 0xFFFF0000u);
            accx0 = fmaf(w0, __uint_as_float(z0 << 16), accx0);
            accy0 = fmaf(w0, __uint_as_float(z0 & 0xFFFF0000u), accy0);
            accx1 = fmaf(w1, __uint_as_float(z1 << 16), accx1);
            accy1 = fmaf(w1, __uint_as_float(z1 & 0xFFFF0000u), accy1);
        }
        if (j < n) {
            unsigned u0 = (unsigned)__shfl((int)u, j, 64);
            unsigned z0 = zb[(long)(u0 & 0xFFFFu) * 64 + lane];
            float w0 = __uint_as_float(u0 & 0xFFFF0000u);
            accx0 = fmaf(w0, __uint_as_float(z0 << 16), accx0);
            accy0 = fmaf(w0, __uint_as_float(z0 & 0xFFFF0000u), accy0);
        }
    }
    float accx = accx0 + accx1, accy = accy0 + accy1;
    for (int off = 32; off; off >>= 1) dsum += __shfl_xor(dsum, off, 64);
    float scale = 1.f / (dsum > 0.f ? dsum : 1.f);
    ((float2*)h)[(long)node * 64 + lane] = make_float2(accx * scale, accy * scale);
}

extern "C" void kernel_launch(void* const* d_in, const int* in_sizes, int n_in,
                              void* d_out, int out_size, void* d_ws, size_t ws_size,
                              hipStream_t stream) {
    const float* nfeats = (const float*)d_in[0];
    const float* efeats = (const float*)d_in[1];
    const float* W_fc   = (const float*)d_in[2];
    const float* W_attn = (const float*)d_in[3];
    const int*   src    = (const int*)d_in[4];
    const int*   dst    = (const int*)d_in[5];
    float* h = (float*)d_out;

    char* ws = (char*)d_ws;
    unsigned* zb     = (unsigned*)ws;                              // 12.8 MB
    float* s_src     = (float*)(ws + (size_t)N_NODES * 64 * 4);
    float* s_dst     = s_src + N_NODES;
    unsigned* Wfrag  = (unsigned*)(s_dst + N_NODES);               // 8192 u32 (32 KB)
    int*   counts    = (int*)(Wfrag + 8192);
    int*   offsets   = counts + N_NODES;                           // N_NODES+1
    int*   blocksums = offsets + N_NODES + 1;                      // 196
    unsigned short* ranks = (unsigned short*)(blocksums + SCAN_BLOCKS + 4);  // 800k u16
    unsigned short* wq    = ranks + N_EDGES;                       // 800k u16
    unsigned* pairs4      = (unsigned*)(wq + N_EDGES);             // 800k u32

    hipMemsetAsync(counts, 0, N_NODES * sizeof(int), stream);
    wfrag_kernel<<<8, 256, 0, stream>>>(W_fc, Wfrag);
    gemm_mfma_kernel<<<(N_NODES + 63) / 64, 256, 0, stream>>>(
        nfeats, Wfrag, W_attn, zb, s_src, s_dst);
    edge_score_hist_kernel<<<(N_EDGES + 255) / 256, 256, 0, stream>>>(
        efeats, W_attn, src, dst, s_src, s_dst, counts, ranks, wq);
    scan1_kernel<<<SCAN_BLOCKS, 256, 0, stream>>>(counts, offsets, blocksums);
    scan2_kernel<<<1, 256, 0, stream>>>(blocksums);
    scan3_kernel<<<SCAN_BLOCKS, 256, 0, stream>>>(offsets, blocksums);
    scatter_kernel<<<(N_EDGES + 255) / 256, 256, 0, stream>>>(
        src, dst, ranks, wq, offsets, pairs4);
    aggregate_kernel<<<(N_NODES + 3) / 4, 256, 0, stream>>>(pairs4, offsets, zb, h);
}